// Round 4
// baseline (2682.625 us; speedup 1.0000x reference)
//
#include <hip/hip_runtime.h>

#define USER_NUM 100000
#define ITEM_NUM 50000
#define N_NODES (USER_NUM + ITEM_NUM)
#define EMB 64
#define N_EDGES 2400000
#define N_LAYERS 3

#define RPB 128                    // rows per bucket
#define NB 1172                    // ceil(150016/128); covers rows 0..150015
#define ROW_PAD 150016             // padded row count (NB*RPB)

#define NCHUNK_A 128               // blocks in bucket_count
#define CH_A 18750                 // edges per bucket_count block (128*18750 = 2.4M)

#define CH2 6144                   // edges per bin_scatter block
#define NCHUNK2 ((N_EDGES + CH2 - 1) / CH2)  // 391

typedef unsigned short u16;

__device__ __forceinline__ float bf2f(u16 h) {
    return __uint_as_float(((unsigned)h) << 16);
}
__device__ __forceinline__ u16 f2bf(float f) {
    unsigned u = __float_as_uint(f);
    unsigned r = 0x7FFFu + ((u >> 16) & 1u);
    return (u16)((u + r) >> 16);
}

// ---------------- concat: user||item f32 -> bf16 ego0 ----------------
__global__ __launch_bounds__(256) void concat_bf16_kernel(
        const float* __restrict__ user_emb, const float* __restrict__ item_emb,
        u16* __restrict__ ego) {
    const int n4 = (N_NODES * EMB) / 4;
    const int user4 = (USER_NUM * EMB) / 4;
    for (int i = blockIdx.x * blockDim.x + threadIdx.x; i < n4;
         i += gridDim.x * blockDim.x) {
        float4 v;
        if (i < user4) {
            v = reinterpret_cast<const float4*>(user_emb)[i];
        } else {
            v = reinterpret_cast<const float4*>(item_emb)[i - user4];
        }
        ushort4 o;
        o.x = f2bf(v.x); o.y = f2bf(v.y); o.z = f2bf(v.z); o.w = f2bf(v.w);
        reinterpret_cast<ushort4*>(ego)[i] = o;
    }
}

// ---------------- A1: per-chunk bucket histogram ----------------
__global__ __launch_bounds__(256) void bucket_count(const int* __restrict__ rows,
                                                    int* __restrict__ cnt) {
    __shared__ int hist[NB];
    const int t = threadIdx.x;
    const int k = blockIdx.x;
    for (int b = t; b < NB; b += 256) hist[b] = 0;
    __syncthreads();
    const int cbase = k * CH_A;
    for (int i = t; i < CH_A; i += 256) {
        const int r = rows[cbase + i];
        atomicAdd(&hist[r >> 7], 1);
    }
    __syncthreads();
    for (int b = t; b < NB; b += 256) cnt[k * NB + b] = hist[b];
}

// ---------------- fused reduce + exclusive scan over NB buckets ----------------
// one block, 256 threads; writes bstart[NB+1] and gcursor[NB] (= bstart copy)
__global__ __launch_bounds__(256) void bucket_scan(const int* __restrict__ cnt,
                                                   int* __restrict__ bstart,
                                                   int* __restrict__ gcursor) {
    __shared__ int tot[NB];
    __shared__ int sums[256];
    const int t = threadIdx.x;
    // column sums (coalesced: adjacent lanes read adjacent buckets)
    for (int b = t; b < NB; b += 256) {
        int v = 0;
        for (int k = 0; k < NCHUNK_A; ++k) v += cnt[k * NB + b];
        tot[b] = v;
    }
    __syncthreads();
    // each thread owns buckets [t*5, t*5+5)
    const int own0 = t * 5;
    int h[5];
    int s = 0;
    for (int j = 0; j < 5; ++j) {
        const int b = own0 + j;
        h[j] = (b < NB) ? tot[b] : 0;
        s += h[j];
    }
    sums[t] = s;
    __syncthreads();
    for (int off = 1; off < 256; off <<= 1) {
        int x = 0;
        if (t >= off) x = sums[t - off];
        __syncthreads();
        sums[t] += x;
        __syncthreads();
    }
    int run = (t == 0) ? 0 : sums[t - 1];
    for (int j = 0; j < 5; ++j) {
        const int b = own0 + j;
        if (b < NB) { bstart[b] = run; gcursor[b] = run; }
        run += h[j];
    }
    if (t == 255) bstart[NB] = N_EDGES;
}

// ---------------- A2: LDS counting-sort scatter into bucket segments ----------
// Packs each edge as (col | rowlocal<<18, val_bits). Bucket regions contiguous;
// within-bucket order nondeterministic (atomic) — fp-sum order only.
__global__ __launch_bounds__(256) void bin_scatter(const int* __restrict__ rows,
                                                   const int* __restrict__ cols,
                                                   const float* __restrict__ vals,
                                                   int* __restrict__ gcursor,
                                                   int2* __restrict__ edges_out) {
    __shared__ int hist[NB];   // counts -> later gb (= gbase - local base)
    __shared__ int base[NB];   // local exclusive scan -> later running cursor
    __shared__ int2 se[CH2];
    __shared__ u16 sb[CH2];
    __shared__ int sums[256];

    const int t = threadIdx.x;
    const int cbase = blockIdx.x * CH2;
    const int cend = min(cbase + CH2, N_EDGES) - cbase;

    for (int b = t; b < NB; b += 256) hist[b] = 0;
    __syncthreads();
    for (int i = t; i < cend; i += 256) {
        const int r = rows[cbase + i];
        atomicAdd(&hist[r >> 7], 1);
    }
    __syncthreads();

    // local exclusive scan of hist -> base
    const int own0 = t * 5;
    int h[5];
    int s = 0;
    for (int j = 0; j < 5; ++j) {
        const int b = own0 + j;
        h[j] = (b < NB) ? hist[b] : 0;
        s += h[j];
    }
    sums[t] = s;
    __syncthreads();
    for (int off = 1; off < 256; off <<= 1) {
        int x = 0;
        if (t >= off) x = sums[t - off];
        __syncthreads();
        sums[t] += x;
        __syncthreads();
    }
    int run = (t == 0) ? 0 : sums[t - 1];
    for (int j = 0; j < 5; ++j) {
        const int b = own0 + j;
        if (b < NB) base[b] = run;
        run += h[j];
    }
    __syncthreads();

    // global segment base per bucket; store gb = gbase - base into hist
    for (int j = 0; j < 5; ++j) {
        const int b = own0 + j;
        if (b < NB) {
            const int hh = h[j];
            int g = 0;
            if (hh) g = atomicAdd(&gcursor[b], hh);
            hist[b] = g - base[b];
        }
    }
    __syncthreads();

    // reorder into LDS, sorted by bucket (base doubles as cursor)
    for (int i = t; i < cend; i += 256) {
        const int r = rows[cbase + i];
        const int c = cols[cbase + i];
        const float v = vals[cbase + i];
        const int b = r >> 7;
        const int slot = atomicAdd(&base[b], 1);
        se[slot] = make_int2(c | ((r & 127) << 18), __float_as_int(v));
        sb[slot] = (u16)b;
    }
    __syncthreads();

    // write out: consecutive slots of one bucket -> consecutive global addrs
    for (int i = t; i < cend; i += 256) {
        const int b = sb[i];
        edges_out[hist[b] + i] = se[i];
    }
}

// ---------------- SpMM: one block per bucket, LDS f32 accumulator -----------
// 16 subgroups x 16 lanes; lane l16 covers dims [4*l16, 4*l16+4).
// acc layout XOR-swizzled per row to spread ds_add banks across subgroups.
__global__ __launch_bounds__(256) void spmm_bucket(const int* __restrict__ bstart,
                                                   const int2* __restrict__ edges,
                                                   const u16* __restrict__ x,
                                                   u16* __restrict__ y) {
    __shared__ float acc[RPB * EMB];  // 32 KB
    const int t = threadIdx.x;
    const int b = blockIdx.x;
    const int s0 = bstart[b];
    const int s1 = bstart[b + 1];

    for (int i = t; i < RPB * EMB; i += 256) acc[i] = 0.f;
    __syncthreads();

    const int sub = t >> 4;
    const int l16 = t & 15;
    const int d0 = 4 * l16;

    for (int e = s0 + sub; e < s1; e += 16) {
        const int2 ev = edges[e];
        const int col = ev.x & 0x3FFFF;
        const int rl = ev.x >> 18;
        const float v = __int_as_float(ev.y);
        const ushort4 xv =
            *reinterpret_cast<const ushort4*>(x + (size_t)col * EMB + d0);
        float* ap = acc + rl * EMB + (d0 ^ ((rl & 7) << 2));
        atomicAdd(ap + 0, v * bf2f(xv.x));
        atomicAdd(ap + 1, v * bf2f(xv.y));
        atomicAdd(ap + 2, v * bf2f(xv.z));
        atomicAdd(ap + 3, v * bf2f(xv.w));
    }
    __syncthreads();

    // flush (unswizzle): 2048 ushort4 groups, coalesced
    const size_t obase = (size_t)b * RPB * EMB;
    for (int i = t; i < (RPB * EMB) / 4; i += 256) {
        const int rl = i >> 4;
        const int g = i & 15;
        const float* ap = acc + rl * EMB + ((4 * g) ^ ((rl & 7) << 2));
        const float4 a = *reinterpret_cast<const float4*>(ap);
        ushort4 o;
        o.x = f2bf(a.x); o.y = f2bf(a.y); o.z = f2bf(a.z); o.w = f2bf(a.w);
        reinterpret_cast<ushort4*>(y + obase)[i] = o;
    }
}

// ---------------- final combine: out = (e1+e2+e3)/3 ----------------
__global__ __launch_bounds__(256) void combine_kernel(const u16* __restrict__ b1,
                                                      const u16* __restrict__ b2,
                                                      const u16* __restrict__ b3,
                                                      float* __restrict__ out) {
    const int n4 = (N_NODES * EMB) / 4;
    const float s = 1.0f / N_LAYERS;
    for (int i = blockIdx.x * blockDim.x + threadIdx.x; i < n4;
         i += gridDim.x * blockDim.x) {
        const ushort4 a = reinterpret_cast<const ushort4*>(b1)[i];
        const ushort4 b = reinterpret_cast<const ushort4*>(b2)[i];
        const ushort4 c = reinterpret_cast<const ushort4*>(b3)[i];
        float4 o;
        o.x = (bf2f(a.x) + bf2f(b.x) + bf2f(c.x)) * s;
        o.y = (bf2f(a.y) + bf2f(b.y) + bf2f(c.y)) * s;
        o.z = (bf2f(a.z) + bf2f(b.z) + bf2f(c.z)) * s;
        o.w = (bf2f(a.w) + bf2f(b.w) + bf2f(c.w)) * s;
        reinterpret_cast<float4*>(out)[i] = o;
    }
}

// ---------------- launch ----------------
extern "C" void kernel_launch(void* const* d_in, const int* in_sizes, int n_in,
                              void* d_out, int out_size, void* d_ws, size_t ws_size,
                              hipStream_t stream) {
    const float* user_emb = (const float*)d_in[0];
    const float* item_emb = (const float*)d_in[1];
    const int*   adj_rows = (const int*)d_in[2];
    const int*   adj_cols = (const int*)d_in[3];
    const float* adj_vals = (const float*)d_in[4];
    float* out = (float*)d_out;

    const size_t nodePad = (size_t)ROW_PAD * EMB;  // 9,601,024 u16

    // workspace layout (~96.6 MB)
    u16* b0 = (u16*)d_ws;
    u16* b1 = b0 + nodePad;
    u16* b2 = b1 + nodePad;
    u16* b3 = b2 + nodePad;
    int2* edges = (int2*)(b3 + nodePad);
    int* cnt = (int*)(edges + N_EDGES);       // NCHUNK_A * NB
    int* bstart = cnt + NCHUNK_A * NB;        // NB+1
    int* gcursor = bstart + (NB + 1);         // NB

    concat_bf16_kernel<<<2048, 256, 0, stream>>>(user_emb, item_emb, b0);
    bucket_count<<<NCHUNK_A, 256, 0, stream>>>(adj_rows, cnt);
    bucket_scan<<<1, 256, 0, stream>>>(cnt, bstart, gcursor);
    bin_scatter<<<NCHUNK2, 256, 0, stream>>>(adj_rows, adj_cols, adj_vals,
                                             gcursor, edges);

    spmm_bucket<<<NB, 256, 0, stream>>>(bstart, edges, b0, b1);
    spmm_bucket<<<NB, 256, 0, stream>>>(bstart, edges, b1, b2);
    spmm_bucket<<<NB, 256, 0, stream>>>(bstart, edges, b2, b3);

    combine_kernel<<<2048, 256, 0, stream>>>(b1, b2, b3, out);
}

// Round 5
// 398.213 us; speedup vs baseline: 6.7367x; 6.7367x over previous
//
#include <hip/hip_runtime.h>

#define USER_NUM 100000
#define ITEM_NUM 50000
#define N_NODES (USER_NUM + ITEM_NUM)
#define EMB 64
#define N_EDGES 2400000
#define N_LAYERS 3

#define RPB 128                    // rows per bucket
#define NB 1172                    // ceil(150016/128)
#define ROW_PAD 150016             // NB*RPB

#define NCHUNK_A 128               // blocks in bucket_count
#define CH_A 18750                 // edges per bucket_count block

#define CH2 6144                   // edges per bin_scatter block
#define NCHUNK2 ((N_EDGES + CH2 - 1) / CH2)  // 391

typedef unsigned short u16;

__device__ __forceinline__ float bf2f(u16 h) {
    return __uint_as_float(((unsigned)h) << 16);
}
__device__ __forceinline__ u16 f2bf(float f) {
    unsigned u = __float_as_uint(f);
    unsigned r = 0x7FFFu + ((u >> 16) & 1u);
    return (u16)((u + r) >> 16);
}

// ---------------- concat: user||item f32 -> bf16 ego0 ----------------
__global__ __launch_bounds__(256) void concat_bf16_kernel(
        const float* __restrict__ user_emb, const float* __restrict__ item_emb,
        u16* __restrict__ ego) {
    const int n4 = (N_NODES * EMB) / 4;
    const int user4 = (USER_NUM * EMB) / 4;
    for (int i = blockIdx.x * blockDim.x + threadIdx.x; i < n4;
         i += gridDim.x * blockDim.x) {
        float4 v;
        if (i < user4) {
            v = reinterpret_cast<const float4*>(user_emb)[i];
        } else {
            v = reinterpret_cast<const float4*>(item_emb)[i - user4];
        }
        ushort4 o;
        o.x = f2bf(v.x); o.y = f2bf(v.y); o.z = f2bf(v.z); o.w = f2bf(v.w);
        reinterpret_cast<ushort4*>(ego)[i] = o;
    }
}

// ---------------- A1: per-chunk bucket histogram ----------------
__global__ __launch_bounds__(256) void bucket_count(const int* __restrict__ rows,
                                                    int* __restrict__ cnt) {
    __shared__ int hist[NB];
    const int t = threadIdx.x;
    const int k = blockIdx.x;
    for (int b = t; b < NB; b += 256) hist[b] = 0;
    __syncthreads();
    const int cbase = k * CH_A;
    for (int i = t; i < CH_A; i += 256) {
        const int r = rows[cbase + i];
        atomicAdd(&hist[r >> 7], 1);
    }
    __syncthreads();
    for (int b = t; b < NB; b += 256) cnt[k * NB + b] = hist[b];
}

// ---------------- fused reduce + exclusive scan over NB buckets --------------
__global__ __launch_bounds__(256) void bucket_scan(const int* __restrict__ cnt,
                                                   int* __restrict__ bstart,
                                                   int* __restrict__ gcursor) {
    __shared__ int tot[NB];
    __shared__ int sums[256];
    const int t = threadIdx.x;
    for (int b = t; b < NB; b += 256) {
        int v = 0;
        for (int k = 0; k < NCHUNK_A; ++k) v += cnt[k * NB + b];
        tot[b] = v;
    }
    __syncthreads();
    const int own0 = t * 5;
    int h[5];
    int s = 0;
    for (int j = 0; j < 5; ++j) {
        const int b = own0 + j;
        h[j] = (b < NB) ? tot[b] : 0;
        s += h[j];
    }
    sums[t] = s;
    __syncthreads();
    for (int off = 1; off < 256; off <<= 1) {
        int x = 0;
        if (t >= off) x = sums[t - off];
        __syncthreads();
        sums[t] += x;
        __syncthreads();
    }
    int run = (t == 0) ? 0 : sums[t - 1];
    for (int j = 0; j < 5; ++j) {
        const int b = own0 + j;
        if (b < NB) { bstart[b] = run; gcursor[b] = run; }
        run += h[j];
    }
    if (t == 255) bstart[NB] = N_EDGES;
}

// ---------------- A2: LDS counting-sort scatter into bucket segments ---------
// Packs each edge as (col | rowlocal<<18, val_bits); bucket regions contiguous.
__global__ __launch_bounds__(256) void bin_scatter(const int* __restrict__ rows,
                                                   const int* __restrict__ cols,
                                                   const float* __restrict__ vals,
                                                   int* __restrict__ gcursor,
                                                   int2* __restrict__ edges_out) {
    __shared__ int hist[NB];   // counts -> later (gbase - local base)
    __shared__ int base[NB];   // local excl scan -> later running cursor
    __shared__ int2 se[CH2];
    __shared__ u16 sb[CH2];
    __shared__ int sums[256];

    const int t = threadIdx.x;
    const int cbase = blockIdx.x * CH2;
    const int cend = min(cbase + CH2, N_EDGES) - cbase;

    for (int b = t; b < NB; b += 256) hist[b] = 0;
    __syncthreads();
    for (int i = t; i < cend; i += 256) {
        const int r = rows[cbase + i];
        atomicAdd(&hist[r >> 7], 1);
    }
    __syncthreads();

    const int own0 = t * 5;
    int h[5];
    int s = 0;
    for (int j = 0; j < 5; ++j) {
        const int b = own0 + j;
        h[j] = (b < NB) ? hist[b] : 0;
        s += h[j];
    }
    sums[t] = s;
    __syncthreads();
    for (int off = 1; off < 256; off <<= 1) {
        int x = 0;
        if (t >= off) x = sums[t - off];
        __syncthreads();
        sums[t] += x;
        __syncthreads();
    }
    int run = (t == 0) ? 0 : sums[t - 1];
    for (int j = 0; j < 5; ++j) {
        const int b = own0 + j;
        if (b < NB) base[b] = run;
        run += h[j];
    }
    __syncthreads();

    for (int j = 0; j < 5; ++j) {
        const int b = own0 + j;
        if (b < NB) {
            const int hh = h[j];
            int g = 0;
            if (hh) g = atomicAdd(&gcursor[b], hh);
            hist[b] = g - base[b];
        }
    }
    __syncthreads();

    for (int i = t; i < cend; i += 256) {
        const int r = rows[cbase + i];
        const int c = cols[cbase + i];
        const float v = vals[cbase + i];
        const int b = r >> 7;
        const int slot = atomicAdd(&base[b], 1);
        se[slot] = make_int2(c | ((r & 127) << 18), __float_as_int(v));
        sb[slot] = (u16)b;
    }
    __syncthreads();

    for (int i = t; i < cend; i += 256) {
        const int b = sb[i];
        edges_out[hist[b] + i] = se[i];
    }
}

// ---------------- B: per-bucket counting sort -> full CSR ----------------
// Input: bucket-contiguous edges (rl packed in bits 18..24). Output: fully
// row-sorted edges (rl stripped) + per-row start offsets. All scatter writes
// stay within the bucket's ~16 KB window (L2-resident).
__global__ __launch_bounds__(256) void row_sort(const int2* __restrict__ edges_in,
                                                const int* __restrict__ bstart,
                                                int* __restrict__ offsets,
                                                int2* __restrict__ edges_out) {
    __shared__ int cnt[RPB];
    __shared__ int cur[RPB];
    const int t = threadIdx.x;
    const int b = blockIdx.x;
    const int s0 = bstart[b];
    const int s1 = bstart[b + 1];

    if (t < RPB) cnt[t] = 0;
    __syncthreads();
    for (int e = s0 + t; e < s1; e += 256)
        atomicAdd(&cnt[((unsigned)edges_in[e].x) >> 18], 1);
    __syncthreads();

    // exclusive scan over 128 row counts (Hillis-Steele)
    if (t < RPB) cur[t] = cnt[t];
    __syncthreads();
    for (int off = 1; off < RPB; off <<= 1) {
        int x = 0;
        if (t < RPB && t >= off) x = cur[t - off];
        __syncthreads();
        if (t < RPB) cur[t] += x;
        __syncthreads();
    }
    if (t < RPB) {
        const int ex = cur[t] - cnt[t];     // exclusive
        cur[t] = ex;                        // becomes the scatter cursor
        offsets[b * RPB + t] = s0 + ex;
    }
    __syncthreads();

    for (int e = s0 + t; e < s1; e += 256) {
        const int2 ev = edges_in[e];
        const int rl = ((unsigned)ev.x) >> 18;
        const int pos = s0 + atomicAdd(&cur[rl], 1);
        edges_out[pos] = make_int2(ev.x & 0x3FFFF, ev.y);
    }
    if (b == NB - 1 && t == 0) offsets[ROW_PAD] = N_EDGES;
}

// ---------------- SpMM (gather, CSR, bf16 in / bf16 out) ----------------
// One wave per row; 4 subgroups of 16 lanes, each processes one edge/iter.
__global__ __launch_bounds__(256) void spmm_gather_bf16(
        const int* __restrict__ offsets, const int2* __restrict__ edges,
        const u16* __restrict__ x, u16* __restrict__ y) {
    const int wid = threadIdx.x >> 6;
    const int lane = threadIdx.x & 63;
    const int sub = lane >> 4;
    const int l16 = lane & 15;
    const int r = blockIdx.x * 4 + wid;
    if (r >= N_NODES) return;

    const int start = offsets[r];
    const int end = offsets[r + 1];
    float4 s = {0.f, 0.f, 0.f, 0.f};
    for (int e = start + sub; e < end; e += 4) {
        const int2 ev = edges[e];
        const float v = __int_as_float(ev.y);
        const ushort4 xv =
            *reinterpret_cast<const ushort4*>(x + (size_t)ev.x * EMB + 4 * l16);
        s.x += v * bf2f(xv.x);
        s.y += v * bf2f(xv.y);
        s.z += v * bf2f(xv.z);
        s.w += v * bf2f(xv.w);
    }
    s.x += __shfl_xor(s.x, 16); s.y += __shfl_xor(s.y, 16);
    s.z += __shfl_xor(s.z, 16); s.w += __shfl_xor(s.w, 16);
    s.x += __shfl_xor(s.x, 32); s.y += __shfl_xor(s.y, 32);
    s.z += __shfl_xor(s.z, 32); s.w += __shfl_xor(s.w, 32);

    if (sub == 0) {
        ushort4 o;
        o.x = f2bf(s.x); o.y = f2bf(s.y); o.z = f2bf(s.z); o.w = f2bf(s.w);
        *reinterpret_cast<ushort4*>(y + (size_t)r * EMB + 4 * l16) = o;
    }
}

// ---------------- final SpMM with fused combine ----------------
// Computes layer-3 row in f32 and writes out = (y1 + y2 + s) / 3 directly.
__global__ __launch_bounds__(256) void spmm_final(
        const int* __restrict__ offsets, const int2* __restrict__ edges,
        const u16* __restrict__ x, const u16* __restrict__ y1,
        const u16* __restrict__ y2, float* __restrict__ out) {
    const int wid = threadIdx.x >> 6;
    const int lane = threadIdx.x & 63;
    const int sub = lane >> 4;
    const int l16 = lane & 15;
    const int r = blockIdx.x * 4 + wid;
    if (r >= N_NODES) return;

    const int start = offsets[r];
    const int end = offsets[r + 1];
    float4 s = {0.f, 0.f, 0.f, 0.f};
    for (int e = start + sub; e < end; e += 4) {
        const int2 ev = edges[e];
        const float v = __int_as_float(ev.y);
        const ushort4 xv =
            *reinterpret_cast<const ushort4*>(x + (size_t)ev.x * EMB + 4 * l16);
        s.x += v * bf2f(xv.x);
        s.y += v * bf2f(xv.y);
        s.z += v * bf2f(xv.z);
        s.w += v * bf2f(xv.w);
    }
    s.x += __shfl_xor(s.x, 16); s.y += __shfl_xor(s.y, 16);
    s.z += __shfl_xor(s.z, 16); s.w += __shfl_xor(s.w, 16);
    s.x += __shfl_xor(s.x, 32); s.y += __shfl_xor(s.y, 32);
    s.z += __shfl_xor(s.z, 32); s.w += __shfl_xor(s.w, 32);

    if (sub == 0) {
        const size_t o = (size_t)r * EMB + 4 * l16;
        const ushort4 a = *reinterpret_cast<const ushort4*>(y1 + o);
        const ushort4 b = *reinterpret_cast<const ushort4*>(y2 + o);
        const float sc = 1.0f / N_LAYERS;
        float4 ov;
        ov.x = (bf2f(a.x) + bf2f(b.x) + s.x) * sc;
        ov.y = (bf2f(a.y) + bf2f(b.y) + s.y) * sc;
        ov.z = (bf2f(a.z) + bf2f(b.z) + s.z) * sc;
        ov.w = (bf2f(a.w) + bf2f(b.w) + s.w) * sc;
        *reinterpret_cast<float4*>(out + o) = ov;
    }
}

// ---------------- launch ----------------
extern "C" void kernel_launch(void* const* d_in, const int* in_sizes, int n_in,
                              void* d_out, int out_size, void* d_ws, size_t ws_size,
                              hipStream_t stream) {
    const float* user_emb = (const float*)d_in[0];
    const float* item_emb = (const float*)d_in[1];
    const int*   adj_rows = (const int*)d_in[2];
    const int*   adj_cols = (const int*)d_in[3];
    const float* adj_vals = (const float*)d_in[4];
    float* out = (float*)d_out;

    const size_t nodeElems = (size_t)N_NODES * EMB;  // 9.6M

    // workspace layout (~96.6 MB; cnt and offsets time-share one region)
    u16* b0 = (u16*)d_ws;                         // 19.2 MB
    u16* b1 = b0 + nodeElems;                     // 19.2 MB
    u16* b2 = b1 + nodeElems;                     // 19.2 MB
    int2* edges_tmp = (int2*)(b2 + nodeElems);    // 19.2 MB
    int2* edges_final = edges_tmp + N_EDGES;      // 19.2 MB
    int* unionReg = (int*)(edges_final + N_EDGES);
    int* cnt = unionReg;                          // NCHUNK_A*NB ints (early)
    int* offsets = unionReg;                      // ROW_PAD+1 ints (late)
    int* bstart = unionReg + 150018;              // NB+1
    int* gcursor = bstart + (NB + 1);             // NB

    concat_bf16_kernel<<<2048, 256, 0, stream>>>(user_emb, item_emb, b0);
    bucket_count<<<NCHUNK_A, 256, 0, stream>>>(adj_rows, cnt);
    bucket_scan<<<1, 256, 0, stream>>>(cnt, bstart, gcursor);
    bin_scatter<<<NCHUNK2, 256, 0, stream>>>(adj_rows, adj_cols, adj_vals,
                                             gcursor, edges_tmp);
    row_sort<<<NB, 256, 0, stream>>>(edges_tmp, bstart, offsets, edges_final);

    const int spmmGrid = N_NODES / 4;  // 37500
    spmm_gather_bf16<<<spmmGrid, 256, 0, stream>>>(offsets, edges_final, b0, b1);
    spmm_gather_bf16<<<spmmGrid, 256, 0, stream>>>(offsets, edges_final, b1, b2);
    spmm_final<<<spmmGrid, 256, 0, stream>>>(offsets, edges_final, b2, b1, b2, out);
}

// Round 6
// 342.447 us; speedup vs baseline: 7.8337x; 1.1628x over previous
//
#include <hip/hip_runtime.h>

#define USER_NUM 100000
#define ITEM_NUM 50000
#define N_NODES (USER_NUM + ITEM_NUM)
#define EMB 64
#define N_EDGES 2400000
#define N_LAYERS 3

#define RPB 128                    // rows per bucket
#define NB 1172                    // ceil(150016/128)
#define ROW_PAD 150016             // NB*RPB

#define NCHUNK_A 128               // blocks in bucket_count
#define CH_A 18750                 // edges per bucket_count block

#define CH2 6144                   // edges per bin_scatter block
#define NCHUNK2 ((N_EDGES + CH2 - 1) / CH2)  // 391

typedef unsigned short u16;

__device__ __forceinline__ float bf2f(u16 h) {
    return __uint_as_float(((unsigned)h) << 16);
}
__device__ __forceinline__ u16 f2bf(float f) {
    unsigned u = __float_as_uint(f);
    unsigned r = 0x7FFFu + ((u >> 16) & 1u);
    return (u16)((u + r) >> 16);
}

// ---------------- concat: user||item f32 -> bf16 ego0 ----------------
__global__ __launch_bounds__(256) void concat_bf16_kernel(
        const float* __restrict__ user_emb, const float* __restrict__ item_emb,
        u16* __restrict__ ego) {
    const int n4 = (N_NODES * EMB) / 4;
    const int user4 = (USER_NUM * EMB) / 4;
    for (int i = blockIdx.x * blockDim.x + threadIdx.x; i < n4;
         i += gridDim.x * blockDim.x) {
        float4 v;
        if (i < user4) {
            v = reinterpret_cast<const float4*>(user_emb)[i];
        } else {
            v = reinterpret_cast<const float4*>(item_emb)[i - user4];
        }
        ushort4 o;
        o.x = f2bf(v.x); o.y = f2bf(v.y); o.z = f2bf(v.z); o.w = f2bf(v.w);
        reinterpret_cast<ushort4*>(ego)[i] = o;
    }
}

// ---------------- A1: per-chunk bucket histogram ----------------
__global__ __launch_bounds__(256) void bucket_count(const int* __restrict__ rows,
                                                    int* __restrict__ cnt) {
    __shared__ int hist[NB];
    const int t = threadIdx.x;
    const int k = blockIdx.x;
    for (int b = t; b < NB; b += 256) hist[b] = 0;
    __syncthreads();
    const int cbase = k * CH_A;
    for (int i = t; i < CH_A; i += 256) {
        const int r = rows[cbase + i];
        atomicAdd(&hist[r >> 7], 1);
    }
    __syncthreads();
    for (int b = t; b < NB; b += 256) cnt[k * NB + b] = hist[b];
}

// ---------------- fused reduce + exclusive scan over NB buckets --------------
__global__ __launch_bounds__(256) void bucket_scan(const int* __restrict__ cnt,
                                                   int* __restrict__ bstart,
                                                   int* __restrict__ gcursor) {
    __shared__ int tot[NB];
    __shared__ int sums[256];
    const int t = threadIdx.x;
    for (int b = t; b < NB; b += 256) {
        int v = 0;
        for (int k = 0; k < NCHUNK_A; ++k) v += cnt[k * NB + b];
        tot[b] = v;
    }
    __syncthreads();
    const int own0 = t * 5;
    int h[5];
    int s = 0;
    for (int j = 0; j < 5; ++j) {
        const int b = own0 + j;
        h[j] = (b < NB) ? tot[b] : 0;
        s += h[j];
    }
    sums[t] = s;
    __syncthreads();
    for (int off = 1; off < 256; off <<= 1) {
        int x = 0;
        if (t >= off) x = sums[t - off];
        __syncthreads();
        sums[t] += x;
        __syncthreads();
    }
    int run = (t == 0) ? 0 : sums[t - 1];
    for (int j = 0; j < 5; ++j) {
        const int b = own0 + j;
        if (b < NB) { bstart[b] = run; gcursor[b] = run; }
        run += h[j];
    }
    if (t == 255) bstart[NB] = N_EDGES;
}

// ---------------- A2: LDS counting-sort scatter into bucket segments ---------
__global__ __launch_bounds__(256) void bin_scatter(const int* __restrict__ rows,
                                                   const int* __restrict__ cols,
                                                   const float* __restrict__ vals,
                                                   int* __restrict__ gcursor,
                                                   int2* __restrict__ edges_out) {
    __shared__ int hist[NB];   // counts -> later (gbase - local base)
    __shared__ int base[NB];   // local excl scan -> later running cursor
    __shared__ int2 se[CH2];
    __shared__ u16 sb[CH2];
    __shared__ int sums[256];

    const int t = threadIdx.x;
    const int cbase = blockIdx.x * CH2;
    const int cend = min(cbase + CH2, N_EDGES) - cbase;

    for (int b = t; b < NB; b += 256) hist[b] = 0;
    __syncthreads();
    for (int i = t; i < cend; i += 256) {
        const int r = rows[cbase + i];
        atomicAdd(&hist[r >> 7], 1);
    }
    __syncthreads();

    const int own0 = t * 5;
    int h[5];
    int s = 0;
    for (int j = 0; j < 5; ++j) {
        const int b = own0 + j;
        h[j] = (b < NB) ? hist[b] : 0;
        s += h[j];
    }
    sums[t] = s;
    __syncthreads();
    for (int off = 1; off < 256; off <<= 1) {
        int x = 0;
        if (t >= off) x = sums[t - off];
        __syncthreads();
        sums[t] += x;
        __syncthreads();
    }
    int run = (t == 0) ? 0 : sums[t - 1];
    for (int j = 0; j < 5; ++j) {
        const int b = own0 + j;
        if (b < NB) base[b] = run;
        run += h[j];
    }
    __syncthreads();

    for (int j = 0; j < 5; ++j) {
        const int b = own0 + j;
        if (b < NB) {
            const int hh = h[j];
            int g = 0;
            if (hh) g = atomicAdd(&gcursor[b], hh);
            hist[b] = g - base[b];
        }
    }
    __syncthreads();

    for (int i = t; i < cend; i += 256) {
        const int r = rows[cbase + i];
        const int c = cols[cbase + i];
        const float v = vals[cbase + i];
        const int b = r >> 7;
        const int slot = atomicAdd(&base[b], 1);
        se[slot] = make_int2(c | ((r & 127) << 18), __float_as_int(v));
        sb[slot] = (u16)b;
    }
    __syncthreads();

    for (int i = t; i < cend; i += 256) {
        const int b = sb[i];
        edges_out[hist[b] + i] = se[i];
    }
}

// ---------------- B: per-bucket counting sort -> full CSR ----------------
__global__ __launch_bounds__(256) void row_sort(const int2* __restrict__ edges_in,
                                                const int* __restrict__ bstart,
                                                int* __restrict__ offsets,
                                                int2* __restrict__ edges_out) {
    __shared__ int cnt[RPB];
    __shared__ int cur[RPB];
    const int t = threadIdx.x;
    const int b = blockIdx.x;
    const int s0 = bstart[b];
    const int s1 = bstart[b + 1];

    if (t < RPB) cnt[t] = 0;
    __syncthreads();
    for (int e = s0 + t; e < s1; e += 256)
        atomicAdd(&cnt[((unsigned)edges_in[e].x) >> 18], 1);
    __syncthreads();

    if (t < RPB) cur[t] = cnt[t];
    __syncthreads();
    for (int off = 1; off < RPB; off <<= 1) {
        int x = 0;
        if (t < RPB && t >= off) x = cur[t - off];
        __syncthreads();
        if (t < RPB) cur[t] += x;
        __syncthreads();
    }
    if (t < RPB) {
        const int ex = cur[t] - cnt[t];
        cur[t] = ex;
        offsets[b * RPB + t] = s0 + ex;
    }
    __syncthreads();

    for (int e = s0 + t; e < s1; e += 256) {
        const int2 ev = edges_in[e];
        const int rl = ((unsigned)ev.x) >> 18;
        const int pos = s0 + atomicAdd(&cur[rl], 1);
        edges_out[pos] = make_int2(ev.x & 0x3FFFF, ev.y);
    }
    if (b == NB - 1 && t == 0) offsets[ROW_PAD] = N_EDGES;
}

// ---------------- row-sum with MLP: 4-edge unrolled gather ----------------
// Sub's edges are {start+sub+4k}. Loads 4 edges, then 4 x-rows, all
// independent -> one latency exposure per row instead of four.
__device__ __forceinline__ float4 row_sum(const int2* __restrict__ edges,
                                          const u16* __restrict__ x,
                                          int start, int end, int sub, int d0) {
    float4 s = {0.f, 0.f, 0.f, 0.f};
    int e = start + sub;
    for (; e + 12 < end; e += 16) {
        const int2 E0 = edges[e];
        const int2 E1 = edges[e + 4];
        const int2 E2 = edges[e + 8];
        const int2 E3 = edges[e + 12];
        const ushort4 x0 = *reinterpret_cast<const ushort4*>(x + (size_t)E0.x * EMB + d0);
        const ushort4 x1 = *reinterpret_cast<const ushort4*>(x + (size_t)E1.x * EMB + d0);
        const ushort4 x2 = *reinterpret_cast<const ushort4*>(x + (size_t)E2.x * EMB + d0);
        const ushort4 x3 = *reinterpret_cast<const ushort4*>(x + (size_t)E3.x * EMB + d0);
        const float v0 = __int_as_float(E0.y);
        const float v1 = __int_as_float(E1.y);
        const float v2 = __int_as_float(E2.y);
        const float v3 = __int_as_float(E3.y);
        s.x += v0 * bf2f(x0.x); s.y += v0 * bf2f(x0.y);
        s.z += v0 * bf2f(x0.z); s.w += v0 * bf2f(x0.w);
        s.x += v1 * bf2f(x1.x); s.y += v1 * bf2f(x1.y);
        s.z += v1 * bf2f(x1.z); s.w += v1 * bf2f(x1.w);
        s.x += v2 * bf2f(x2.x); s.y += v2 * bf2f(x2.y);
        s.z += v2 * bf2f(x2.z); s.w += v2 * bf2f(x2.w);
        s.x += v3 * bf2f(x3.x); s.y += v3 * bf2f(x3.y);
        s.z += v3 * bf2f(x3.z); s.w += v3 * bf2f(x3.w);
    }
    // <=3 of this sub's edges remain
    if (e + 4 < end) {
        const int2 E0 = edges[e];
        const int2 E1 = edges[e + 4];
        const ushort4 x0 = *reinterpret_cast<const ushort4*>(x + (size_t)E0.x * EMB + d0);
        const ushort4 x1 = *reinterpret_cast<const ushort4*>(x + (size_t)E1.x * EMB + d0);
        const float v0 = __int_as_float(E0.y);
        const float v1 = __int_as_float(E1.y);
        s.x += v0 * bf2f(x0.x); s.y += v0 * bf2f(x0.y);
        s.z += v0 * bf2f(x0.z); s.w += v0 * bf2f(x0.w);
        s.x += v1 * bf2f(x1.x); s.y += v1 * bf2f(x1.y);
        s.z += v1 * bf2f(x1.z); s.w += v1 * bf2f(x1.w);
        e += 8;
    }
    if (e < end) {
        const int2 E0 = edges[e];
        const ushort4 x0 = *reinterpret_cast<const ushort4*>(x + (size_t)E0.x * EMB + d0);
        const float v0 = __int_as_float(E0.y);
        s.x += v0 * bf2f(x0.x); s.y += v0 * bf2f(x0.y);
        s.z += v0 * bf2f(x0.z); s.w += v0 * bf2f(x0.w);
    }
    return s;
}

// ---------------- SpMM (gather, CSR, bf16 in / bf16 out) ----------------
__global__ __launch_bounds__(256) void spmm_gather_bf16(
        const int* __restrict__ offsets, const int2* __restrict__ edges,
        const u16* __restrict__ x, u16* __restrict__ y) {
    const int wid = threadIdx.x >> 6;
    const int lane = threadIdx.x & 63;
    const int sub = lane >> 4;
    const int l16 = lane & 15;
    const int r = blockIdx.x * 4 + wid;
    if (r >= N_NODES) return;

    float4 s = row_sum(edges, x, offsets[r], offsets[r + 1], sub, 4 * l16);

    s.x += __shfl_xor(s.x, 16); s.y += __shfl_xor(s.y, 16);
    s.z += __shfl_xor(s.z, 16); s.w += __shfl_xor(s.w, 16);
    s.x += __shfl_xor(s.x, 32); s.y += __shfl_xor(s.y, 32);
    s.z += __shfl_xor(s.z, 32); s.w += __shfl_xor(s.w, 32);

    if (sub == 0) {
        ushort4 o;
        o.x = f2bf(s.x); o.y = f2bf(s.y); o.z = f2bf(s.z); o.w = f2bf(s.w);
        *reinterpret_cast<ushort4*>(y + (size_t)r * EMB + 4 * l16) = o;
    }
}

// ---------------- final SpMM with fused combine ----------------
__global__ __launch_bounds__(256) void spmm_final(
        const int* __restrict__ offsets, const int2* __restrict__ edges,
        const u16* __restrict__ x, const u16* __restrict__ y1,
        const u16* __restrict__ y2, float* __restrict__ out) {
    const int wid = threadIdx.x >> 6;
    const int lane = threadIdx.x & 63;
    const int sub = lane >> 4;
    const int l16 = lane & 15;
    const int r = blockIdx.x * 4 + wid;
    if (r >= N_NODES) return;

    float4 s = row_sum(edges, x, offsets[r], offsets[r + 1], sub, 4 * l16);

    s.x += __shfl_xor(s.x, 16); s.y += __shfl_xor(s.y, 16);
    s.z += __shfl_xor(s.z, 16); s.w += __shfl_xor(s.w, 16);
    s.x += __shfl_xor(s.x, 32); s.y += __shfl_xor(s.y, 32);
    s.z += __shfl_xor(s.z, 32); s.w += __shfl_xor(s.w, 32);

    if (sub == 0) {
        const size_t o = (size_t)r * EMB + 4 * l16;
        const ushort4 a = *reinterpret_cast<const ushort4*>(y1 + o);
        const ushort4 b = *reinterpret_cast<const ushort4*>(y2 + o);
        const float sc = 1.0f / N_LAYERS;
        float4 ov;
        ov.x = (bf2f(a.x) + bf2f(b.x) + s.x) * sc;
        ov.y = (bf2f(a.y) + bf2f(b.y) + s.y) * sc;
        ov.z = (bf2f(a.z) + bf2f(b.z) + s.z) * sc;
        ov.w = (bf2f(a.w) + bf2f(b.w) + s.w) * sc;
        *reinterpret_cast<float4*>(out + o) = ov;
    }
}

// ---------------- launch ----------------
extern "C" void kernel_launch(void* const* d_in, const int* in_sizes, int n_in,
                              void* d_out, int out_size, void* d_ws, size_t ws_size,
                              hipStream_t stream) {
    const float* user_emb = (const float*)d_in[0];
    const float* item_emb = (const float*)d_in[1];
    const int*   adj_rows = (const int*)d_in[2];
    const int*   adj_cols = (const int*)d_in[3];
    const float* adj_vals = (const float*)d_in[4];
    float* out = (float*)d_out;

    const size_t nodeElems = (size_t)N_NODES * EMB;  // 9.6M

    // workspace layout (~96.6 MB; cnt and offsets time-share one region)
    u16* b0 = (u16*)d_ws;                         // 19.2 MB
    u16* b1 = b0 + nodeElems;                     // 19.2 MB
    u16* b2 = b1 + nodeElems;                     // 19.2 MB
    int2* edges_tmp = (int2*)(b2 + nodeElems);    // 19.2 MB
    int2* edges_final = edges_tmp + N_EDGES;      // 19.2 MB
    int* unionReg = (int*)(edges_final + N_EDGES);
    int* cnt = unionReg;                          // NCHUNK_A*NB ints (early)
    int* offsets = unionReg;                      // ROW_PAD+1 ints (late)
    int* bstart = unionReg + 150018;              // NB+1
    int* gcursor = bstart + (NB + 1);             // NB

    concat_bf16_kernel<<<2048, 256, 0, stream>>>(user_emb, item_emb, b0);
    bucket_count<<<NCHUNK_A, 256, 0, stream>>>(adj_rows, cnt);
    bucket_scan<<<1, 256, 0, stream>>>(cnt, bstart, gcursor);
    bin_scatter<<<NCHUNK2, 256, 0, stream>>>(adj_rows, adj_cols, adj_vals,
                                             gcursor, edges_tmp);
    row_sort<<<NB, 256, 0, stream>>>(edges_tmp, bstart, offsets, edges_final);

    const int spmmGrid = N_NODES / 4;  // 37500
    spmm_gather_bf16<<<spmmGrid, 256, 0, stream>>>(offsets, edges_final, b0, b1);
    spmm_gather_bf16<<<spmmGrid, 256, 0, stream>>>(offsets, edges_final, b1, b2);
    spmm_final<<<spmmGrid, 256, 0, stream>>>(offsets, edges_final, b2, b1, b2, out);
}

// Round 7
// 325.547 us; speedup vs baseline: 8.2404x; 1.0519x over previous
//
#include <hip/hip_runtime.h>

#define USER_NUM 100000
#define ITEM_NUM 50000
#define N_NODES (USER_NUM + ITEM_NUM)
#define EMB 64
#define N_EDGES 2400000
#define N_LAYERS 3

#define RPB 512                    // rows per bucket
#define RL_SH 9                    // log2(RPB)
#define NB 293                     // ceil(150016/512)
#define ROW_PAD 150016             // NB*RPB

#define NCHUNK_A 512               // blocks in bucket_count
#define CH_A 4688                  // edges per bucket_count block (512*4688 >= 2.4M)

#define CH2 4096                   // edges per bin_scatter block
#define NCHUNK2 ((N_EDGES + CH2 - 1) / CH2)  // 586

typedef unsigned short u16;

__device__ __forceinline__ float bf2f(u16 h) {
    return __uint_as_float(((unsigned)h) << 16);
}
__device__ __forceinline__ u16 f2bf(float f) {
    unsigned u = __float_as_uint(f);
    unsigned r = 0x7FFFu + ((u >> 16) & 1u);
    return (u16)((u + r) >> 16);
}

// ---------------- concat: user||item f32 -> bf16 ego0 ----------------
__global__ __launch_bounds__(256) void concat_bf16_kernel(
        const float* __restrict__ user_emb, const float* __restrict__ item_emb,
        u16* __restrict__ ego) {
    const int n4 = (N_NODES * EMB) / 4;
    const int user4 = (USER_NUM * EMB) / 4;
    for (int i = blockIdx.x * blockDim.x + threadIdx.x; i < n4;
         i += gridDim.x * blockDim.x) {
        float4 v;
        if (i < user4) {
            v = reinterpret_cast<const float4*>(user_emb)[i];
        } else {
            v = reinterpret_cast<const float4*>(item_emb)[i - user4];
        }
        ushort4 o;
        o.x = f2bf(v.x); o.y = f2bf(v.y); o.z = f2bf(v.z); o.w = f2bf(v.w);
        reinterpret_cast<ushort4*>(ego)[i] = o;
    }
}

// ---------------- A1: per-chunk bucket histogram ----------------
__global__ __launch_bounds__(256) void bucket_count(const int* __restrict__ rows,
                                                    int* __restrict__ cnt) {
    __shared__ int hist[NB];
    const int t = threadIdx.x;
    const int k = blockIdx.x;
    for (int b = t; b < NB; b += 256) hist[b] = 0;
    __syncthreads();
    const int cbase = k * CH_A;
    const int cend = min(cbase + CH_A, N_EDGES);
    for (int i = cbase + t; i < cend; i += 256) {
        atomicAdd(&hist[rows[i] >> RL_SH], 1);
    }
    __syncthreads();
    for (int b = t; b < NB; b += 256) cnt[k * NB + b] = hist[b];
}

// ---------------- fused reduce + exclusive scan over NB buckets --------------
__global__ __launch_bounds__(256) void bucket_scan(const int* __restrict__ cnt,
                                                   int* __restrict__ bstart,
                                                   int* __restrict__ gcursor) {
    __shared__ int tot[NB];
    __shared__ int sums[256];
    const int t = threadIdx.x;
    for (int b = t; b < NB; b += 256) {
        int v = 0;
        for (int k = 0; k < NCHUNK_A; ++k) v += cnt[k * NB + b];
        tot[b] = v;
    }
    __syncthreads();
    const int own0 = t * 2;
    int h0 = (own0 < NB) ? tot[own0] : 0;
    int h1 = (own0 + 1 < NB) ? tot[own0 + 1] : 0;
    sums[t] = h0 + h1;
    __syncthreads();
    for (int off = 1; off < 256; off <<= 1) {
        int x = 0;
        if (t >= off) x = sums[t - off];
        __syncthreads();
        sums[t] += x;
        __syncthreads();
    }
    int run = (t == 0) ? 0 : sums[t - 1];
    if (own0 < NB) { bstart[own0] = run; gcursor[own0] = run; }
    if (own0 + 1 < NB) { bstart[own0 + 1] = run + h0; gcursor[own0 + 1] = run + h0; }
    if (t == 255) bstart[NB] = N_EDGES;
}

// ---------------- A2: LDS counting-sort scatter into bucket segments ---------
// Packs each edge as (col | rowlocal<<18, val_bits); bucket regions contiguous.
__global__ __launch_bounds__(256) void bin_scatter(const int* __restrict__ rows,
                                                   const int* __restrict__ cols,
                                                   const float* __restrict__ vals,
                                                   int* __restrict__ gcursor,
                                                   int2* __restrict__ edges_out) {
    __shared__ int hist[NB];   // counts -> later (gbase - local base)
    __shared__ int base[NB];   // local excl scan -> later running cursor
    __shared__ int2 se[CH2];
    __shared__ u16 sb[CH2];
    __shared__ int sums[256];

    const int t = threadIdx.x;
    const int cbase = blockIdx.x * CH2;
    const int cend = min(cbase + CH2, N_EDGES) - cbase;

    for (int b = t; b < NB; b += 256) hist[b] = 0;
    __syncthreads();
    for (int i = t; i < cend; i += 256) {
        atomicAdd(&hist[rows[cbase + i] >> RL_SH], 1);
    }
    __syncthreads();

    const int own0 = t * 2;
    int h0 = (own0 < NB) ? hist[own0] : 0;
    int h1 = (own0 + 1 < NB) ? hist[own0 + 1] : 0;
    sums[t] = h0 + h1;
    __syncthreads();
    for (int off = 1; off < 256; off <<= 1) {
        int x = 0;
        if (t >= off) x = sums[t - off];
        __syncthreads();
        sums[t] += x;
        __syncthreads();
    }
    int run = (t == 0) ? 0 : sums[t - 1];
    if (own0 < NB) base[own0] = run;
    if (own0 + 1 < NB) base[own0 + 1] = run + h0;
    __syncthreads();

    // global segment base per bucket; store (gbase - localbase) into hist
    if (own0 < NB) {
        int g = 0;
        if (h0) g = atomicAdd(&gcursor[own0], h0);
        hist[own0] = g - base[own0];
    }
    if (own0 + 1 < NB) {
        int g = 0;
        if (h1) g = atomicAdd(&gcursor[own0 + 1], h1);
        hist[own0 + 1] = g - base[own0 + 1];
    }
    __syncthreads();

    for (int i = t; i < cend; i += 256) {
        const int r = rows[cbase + i];
        const int c = cols[cbase + i];
        const float v = vals[cbase + i];
        const int b = r >> RL_SH;
        const int slot = atomicAdd(&base[b], 1);
        se[slot] = make_int2(c | ((r & (RPB - 1)) << 18), __float_as_int(v));
        sb[slot] = (u16)b;
    }
    __syncthreads();

    for (int i = t; i < cend; i += 256) {
        const int b = sb[i];
        edges_out[hist[b] + i] = se[i];
    }
}

// ---------------- B: per-bucket counting sort -> full CSR ----------------
// One block per 512-row bucket; scatter window ~65 KB (L2-resident).
__global__ __launch_bounds__(256) void row_sort(const int2* __restrict__ edges_in,
                                                const int* __restrict__ bstart,
                                                int* __restrict__ offsets,
                                                int2* __restrict__ edges_out) {
    __shared__ int cnt[RPB];
    __shared__ int cur[RPB];
    __shared__ int sums[256];
    const int t = threadIdx.x;
    const int b = blockIdx.x;
    const int s0 = bstart[b];
    const int s1 = bstart[b + 1];

    cnt[t] = 0;
    cnt[t + 256] = 0;
    __syncthreads();
    for (int e = s0 + t; e < s1; e += 256)
        atomicAdd(&cnt[((unsigned)edges_in[e].x) >> 18], 1);
    __syncthreads();

    // exclusive scan over 512 row counts; thread t owns rows 2t, 2t+1
    const int c0 = cnt[2 * t];
    const int c1 = cnt[2 * t + 1];
    sums[t] = c0 + c1;
    __syncthreads();
    for (int off = 1; off < 256; off <<= 1) {
        int x = 0;
        if (t >= off) x = sums[t - off];
        __syncthreads();
        sums[t] += x;
        __syncthreads();
    }
    const int run = (t == 0) ? 0 : sums[t - 1];
    cur[2 * t] = run;
    cur[2 * t + 1] = run + c0;
    offsets[b * RPB + 2 * t] = s0 + run;
    offsets[b * RPB + 2 * t + 1] = s0 + run + c0;
    __syncthreads();

    for (int e = s0 + t; e < s1; e += 256) {
        const int2 ev = edges_in[e];
        const int rl = ((unsigned)ev.x) >> 18;
        const int pos = s0 + atomicAdd(&cur[rl], 1);
        edges_out[pos] = make_int2(ev.x & 0x3FFFF, ev.y);
    }
    if (b == NB - 1 && t == 0) offsets[ROW_PAD] = N_EDGES;
}

// ---------------- row-sum with MLP: 4-edge unrolled gather ----------------
__device__ __forceinline__ float4 row_sum(const int2* __restrict__ edges,
                                          const u16* __restrict__ x,
                                          int start, int end, int sub, int d0) {
    float4 s = {0.f, 0.f, 0.f, 0.f};
    int e = start + sub;
    for (; e + 12 < end; e += 16) {
        const int2 E0 = edges[e];
        const int2 E1 = edges[e + 4];
        const int2 E2 = edges[e + 8];
        const int2 E3 = edges[e + 12];
        const ushort4 x0 = *reinterpret_cast<const ushort4*>(x + (size_t)E0.x * EMB + d0);
        const ushort4 x1 = *reinterpret_cast<const ushort4*>(x + (size_t)E1.x * EMB + d0);
        const ushort4 x2 = *reinterpret_cast<const ushort4*>(x + (size_t)E2.x * EMB + d0);
        const ushort4 x3 = *reinterpret_cast<const ushort4*>(x + (size_t)E3.x * EMB + d0);
        const float v0 = __int_as_float(E0.y);
        const float v1 = __int_as_float(E1.y);
        const float v2 = __int_as_float(E2.y);
        const float v3 = __int_as_float(E3.y);
        s.x += v0 * bf2f(x0.x); s.y += v0 * bf2f(x0.y);
        s.z += v0 * bf2f(x0.z); s.w += v0 * bf2f(x0.w);
        s.x += v1 * bf2f(x1.x); s.y += v1 * bf2f(x1.y);
        s.z += v1 * bf2f(x1.z); s.w += v1 * bf2f(x1.w);
        s.x += v2 * bf2f(x2.x); s.y += v2 * bf2f(x2.y);
        s.z += v2 * bf2f(x2.z); s.w += v2 * bf2f(x2.w);
        s.x += v3 * bf2f(x3.x); s.y += v3 * bf2f(x3.y);
        s.z += v3 * bf2f(x3.z); s.w += v3 * bf2f(x3.w);
    }
    if (e + 4 < end) {
        const int2 E0 = edges[e];
        const int2 E1 = edges[e + 4];
        const ushort4 x0 = *reinterpret_cast<const ushort4*>(x + (size_t)E0.x * EMB + d0);
        const ushort4 x1 = *reinterpret_cast<const ushort4*>(x + (size_t)E1.x * EMB + d0);
        const float v0 = __int_as_float(E0.y);
        const float v1 = __int_as_float(E1.y);
        s.x += v0 * bf2f(x0.x); s.y += v0 * bf2f(x0.y);
        s.z += v0 * bf2f(x0.z); s.w += v0 * bf2f(x0.w);
        s.x += v1 * bf2f(x1.x); s.y += v1 * bf2f(x1.y);
        s.z += v1 * bf2f(x1.z); s.w += v1 * bf2f(x1.w);
        e += 8;
    }
    if (e < end) {
        const int2 E0 = edges[e];
        const ushort4 x0 = *reinterpret_cast<const ushort4*>(x + (size_t)E0.x * EMB + d0);
        const float v0 = __int_as_float(E0.y);
        s.x += v0 * bf2f(x0.x); s.y += v0 * bf2f(x0.y);
        s.z += v0 * bf2f(x0.z); s.w += v0 * bf2f(x0.w);
    }
    return s;
}

// ---------------- SpMM (gather, CSR, bf16 in / bf16 out) ----------------
__global__ __launch_bounds__(256) void spmm_gather_bf16(
        const int* __restrict__ offsets, const int2* __restrict__ edges,
        const u16* __restrict__ x, u16* __restrict__ y) {
    const int wid = threadIdx.x >> 6;
    const int lane = threadIdx.x & 63;
    const int sub = lane >> 4;
    const int l16 = lane & 15;
    const int r = blockIdx.x * 4 + wid;
    if (r >= N_NODES) return;

    float4 s = row_sum(edges, x, offsets[r], offsets[r + 1], sub, 4 * l16);

    s.x += __shfl_xor(s.x, 16); s.y += __shfl_xor(s.y, 16);
    s.z += __shfl_xor(s.z, 16); s.w += __shfl_xor(s.w, 16);
    s.x += __shfl_xor(s.x, 32); s.y += __shfl_xor(s.y, 32);
    s.z += __shfl_xor(s.z, 32); s.w += __shfl_xor(s.w, 32);

    if (sub == 0) {
        ushort4 o;
        o.x = f2bf(s.x); o.y = f2bf(s.y); o.z = f2bf(s.z); o.w = f2bf(s.w);
        *reinterpret_cast<ushort4*>(y + (size_t)r * EMB + 4 * l16) = o;
    }
}

// ---------------- final SpMM with fused combine ----------------
__global__ __launch_bounds__(256) void spmm_final(
        const int* __restrict__ offsets, const int2* __restrict__ edges,
        const u16* __restrict__ x, const u16* __restrict__ y1,
        const u16* __restrict__ y2, float* __restrict__ out) {
    const int wid = threadIdx.x >> 6;
    const int lane = threadIdx.x & 63;
    const int sub = lane >> 4;
    const int l16 = lane & 15;
    const int r = blockIdx.x * 4 + wid;
    if (r >= N_NODES) return;

    float4 s = row_sum(edges, x, offsets[r], offsets[r + 1], sub, 4 * l16);

    s.x += __shfl_xor(s.x, 16); s.y += __shfl_xor(s.y, 16);
    s.z += __shfl_xor(s.z, 16); s.w += __shfl_xor(s.w, 16);
    s.x += __shfl_xor(s.x, 32); s.y += __shfl_xor(s.y, 32);
    s.z += __shfl_xor(s.z, 32); s.w += __shfl_xor(s.w, 32);

    if (sub == 0) {
        const size_t o = (size_t)r * EMB + 4 * l16;
        const ushort4 a = *reinterpret_cast<const ushort4*>(y1 + o);
        const ushort4 b = *reinterpret_cast<const ushort4*>(y2 + o);
        const float sc = 1.0f / N_LAYERS;
        float4 ov;
        ov.x = (bf2f(a.x) + bf2f(b.x) + s.x) * sc;
        ov.y = (bf2f(a.y) + bf2f(b.y) + s.y) * sc;
        ov.z = (bf2f(a.z) + bf2f(b.z) + s.z) * sc;
        ov.w = (bf2f(a.w) + bf2f(b.w) + s.w) * sc;
        *reinterpret_cast<float4*>(out + o) = ov;
    }
}

// ---------------- launch ----------------
extern "C" void kernel_launch(void* const* d_in, const int* in_sizes, int n_in,
                              void* d_out, int out_size, void* d_ws, size_t ws_size,
                              hipStream_t stream) {
    const float* user_emb = (const float*)d_in[0];
    const float* item_emb = (const float*)d_in[1];
    const int*   adj_rows = (const int*)d_in[2];
    const int*   adj_cols = (const int*)d_in[3];
    const float* adj_vals = (const float*)d_in[4];
    float* out = (float*)d_out;

    const size_t nodeElems = (size_t)N_NODES * EMB;  // 9.6M

    // workspace layout (~96.6 MB; cnt and offsets time-share one region)
    u16* b0 = (u16*)d_ws;                         // 19.2 MB
    u16* b1 = b0 + nodeElems;                     // 19.2 MB
    u16* b2 = b1 + nodeElems;                     // 19.2 MB
    int2* edges_tmp = (int2*)(b2 + nodeElems);    // 19.2 MB
    int2* edges_final = edges_tmp + N_EDGES;      // 19.2 MB
    int* unionReg = (int*)(edges_final + N_EDGES);
    int* cnt = unionReg;                          // NCHUNK_A*NB = 150016 ints
    int* offsets = unionReg;                      // ROW_PAD+1 = 150017 ints
    int* bstart = unionReg + 150024;              // NB+1
    int* gcursor = bstart + (NB + 1);             // NB

    concat_bf16_kernel<<<2048, 256, 0, stream>>>(user_emb, item_emb, b0);
    bucket_count<<<NCHUNK_A, 256, 0, stream>>>(adj_rows, cnt);
    bucket_scan<<<1, 256, 0, stream>>>(cnt, bstart, gcursor);
    bin_scatter<<<NCHUNK2, 256, 0, stream>>>(adj_rows, adj_cols, adj_vals,
                                             gcursor, edges_tmp);
    row_sort<<<NB, 256, 0, stream>>>(edges_tmp, bstart, offsets, edges_final);

    const int spmmGrid = N_NODES / 4;  // 37500
    spmm_gather_bf16<<<spmmGrid, 256, 0, stream>>>(offsets, edges_final, b0, b1);
    spmm_gather_bf16<<<spmmGrid, 256, 0, stream>>>(offsets, edges_final, b1, b2);
    spmm_final<<<spmmGrid, 256, 0, stream>>>(offsets, edges_final, b2, b1, b2, out);
}

// Round 8
// 297.713 us; speedup vs baseline: 9.0108x; 1.0935x over previous
//
#include <hip/hip_runtime.h>

#define USER_NUM 100000
#define ITEM_NUM 50000
#define N_NODES (USER_NUM + ITEM_NUM)
#define EMB 64
#define N_EDGES 2400000
#define N_LAYERS 3

#define RPB 512                    // rows per bucket
#define RL_SH 9                    // log2(RPB)
#define NB 293                     // ceil(150016/512)
#define ROW_PAD 150016             // NB*RPB

#define NCHUNK_A 512               // blocks in bucket_count
#define CH_A 4688                  // edges per bucket_count block

#define CH2 4096                   // edges per bin_scatter block
#define NCHUNK2 ((N_EDGES + CH2 - 1) / CH2)  // 586

typedef unsigned short u16;

__device__ __forceinline__ float bf2f(u16 h) {
    return __uint_as_float(((unsigned)h) << 16);
}
__device__ __forceinline__ u16 f2bf(float f) {
    unsigned u = __float_as_uint(f);
    unsigned r = 0x7FFFu + ((u >> 16) & 1u);
    return (u16)((u + r) >> 16);
}

// ---------------- concat: user||item f32 -> bf16 ego0 ----------------
__global__ __launch_bounds__(256) void concat_bf16_kernel(
        const float* __restrict__ user_emb, const float* __restrict__ item_emb,
        u16* __restrict__ ego) {
    const int n4 = (N_NODES * EMB) / 4;
    const int user4 = (USER_NUM * EMB) / 4;
    for (int i = blockIdx.x * blockDim.x + threadIdx.x; i < n4;
         i += gridDim.x * blockDim.x) {
        float4 v;
        if (i < user4) {
            v = reinterpret_cast<const float4*>(user_emb)[i];
        } else {
            v = reinterpret_cast<const float4*>(item_emb)[i - user4];
        }
        ushort4 o;
        o.x = f2bf(v.x); o.y = f2bf(v.y); o.z = f2bf(v.z); o.w = f2bf(v.w);
        reinterpret_cast<ushort4*>(ego)[i] = o;
    }
}

// ---------------- A1: per-chunk bucket histogram ----------------
__global__ __launch_bounds__(256) void bucket_count(const int* __restrict__ rows,
                                                    int* __restrict__ cnt) {
    __shared__ int hist[NB];
    const int t = threadIdx.x;
    const int k = blockIdx.x;
    for (int b = t; b < NB; b += 256) hist[b] = 0;
    __syncthreads();
    const int cbase = k * CH_A;
    const int cend = min(cbase + CH_A, N_EDGES);
    for (int i = cbase + t; i < cend; i += 256) {
        atomicAdd(&hist[rows[i] >> RL_SH], 1);
    }
    __syncthreads();
    for (int b = t; b < NB; b += 256) cnt[k * NB + b] = hist[b];
}

// ---------------- fused reduce + exclusive scan over NB buckets --------------
__global__ __launch_bounds__(256) void bucket_scan(const int* __restrict__ cnt,
                                                   int* __restrict__ bstart,
                                                   int* __restrict__ gcursor) {
    __shared__ int tot[NB];
    __shared__ int sums[256];
    const int t = threadIdx.x;
    for (int b = t; b < NB; b += 256) {
        int v = 0;
        for (int k = 0; k < NCHUNK_A; ++k) v += cnt[k * NB + b];
        tot[b] = v;
    }
    __syncthreads();
    const int own0 = t * 2;
    int h0 = (own0 < NB) ? tot[own0] : 0;
    int h1 = (own0 + 1 < NB) ? tot[own0 + 1] : 0;
    sums[t] = h0 + h1;
    __syncthreads();
    for (int off = 1; off < 256; off <<= 1) {
        int x = 0;
        if (t >= off) x = sums[t - off];
        __syncthreads();
        sums[t] += x;
        __syncthreads();
    }
    int run = (t == 0) ? 0 : sums[t - 1];
    if (own0 < NB) { bstart[own0] = run; gcursor[own0] = run; }
    if (own0 + 1 < NB) { bstart[own0 + 1] = run + h0; gcursor[own0 + 1] = run + h0; }
    if (t == 255) bstart[NB] = N_EDGES;
}

// ---------------- A2: LDS counting-sort scatter into bucket segments ---------
__global__ __launch_bounds__(256) void bin_scatter(const int* __restrict__ rows,
                                                   const int* __restrict__ cols,
                                                   const float* __restrict__ vals,
                                                   int* __restrict__ gcursor,
                                                   int2* __restrict__ edges_out) {
    __shared__ int hist[NB];   // counts -> later (gbase - local base)
    __shared__ int base[NB];   // local excl scan -> later running cursor
    __shared__ int2 se[CH2];
    __shared__ u16 sb[CH2];
    __shared__ int sums[256];

    const int t = threadIdx.x;
    const int cbase = blockIdx.x * CH2;
    const int cend = min(cbase + CH2, N_EDGES) - cbase;

    for (int b = t; b < NB; b += 256) hist[b] = 0;
    __syncthreads();
    for (int i = t; i < cend; i += 256) {
        atomicAdd(&hist[rows[cbase + i] >> RL_SH], 1);
    }
    __syncthreads();

    const int own0 = t * 2;
    int h0 = (own0 < NB) ? hist[own0] : 0;
    int h1 = (own0 + 1 < NB) ? hist[own0 + 1] : 0;
    sums[t] = h0 + h1;
    __syncthreads();
    for (int off = 1; off < 256; off <<= 1) {
        int x = 0;
        if (t >= off) x = sums[t - off];
        __syncthreads();
        sums[t] += x;
        __syncthreads();
    }
    int run = (t == 0) ? 0 : sums[t - 1];
    if (own0 < NB) base[own0] = run;
    if (own0 + 1 < NB) base[own0 + 1] = run + h0;
    __syncthreads();

    if (own0 < NB) {
        int g = 0;
        if (h0) g = atomicAdd(&gcursor[own0], h0);
        hist[own0] = g - base[own0];
    }
    if (own0 + 1 < NB) {
        int g = 0;
        if (h1) g = atomicAdd(&gcursor[own0 + 1], h1);
        hist[own0 + 1] = g - base[own0 + 1];
    }
    __syncthreads();

    for (int i = t; i < cend; i += 256) {
        const int r = rows[cbase + i];
        const int c = cols[cbase + i];
        const float v = vals[cbase + i];
        const int b = r >> RL_SH;
        const int slot = atomicAdd(&base[b], 1);
        se[slot] = make_int2(c | ((r & (RPB - 1)) << 18), __float_as_int(v));
        sb[slot] = (u16)b;
    }
    __syncthreads();

    for (int i = t; i < cend; i += 256) {
        const int b = sb[i];
        edges_out[hist[b] + i] = se[i];
    }
}

// ---------------- B: per-bucket counting sort -> full CSR ----------------
__global__ __launch_bounds__(256) void row_sort(const int2* __restrict__ edges_in,
                                                const int* __restrict__ bstart,
                                                int* __restrict__ offsets,
                                                int2* __restrict__ edges_out) {
    __shared__ int cnt[RPB];
    __shared__ int cur[RPB];
    __shared__ int sums[256];
    const int t = threadIdx.x;
    const int b = blockIdx.x;
    const int s0 = bstart[b];
    const int s1 = bstart[b + 1];

    cnt[t] = 0;
    cnt[t + 256] = 0;
    __syncthreads();
    for (int e = s0 + t; e < s1; e += 256)
        atomicAdd(&cnt[((unsigned)edges_in[e].x) >> 18], 1);
    __syncthreads();

    const int c0 = cnt[2 * t];
    const int c1 = cnt[2 * t + 1];
    sums[t] = c0 + c1;
    __syncthreads();
    for (int off = 1; off < 256; off <<= 1) {
        int x = 0;
        if (t >= off) x = sums[t - off];
        __syncthreads();
        sums[t] += x;
        __syncthreads();
    }
    const int run = (t == 0) ? 0 : sums[t - 1];
    cur[2 * t] = run;
    cur[2 * t + 1] = run + c0;
    offsets[b * RPB + 2 * t] = s0 + run;
    offsets[b * RPB + 2 * t + 1] = s0 + run + c0;
    __syncthreads();

    for (int e = s0 + t; e < s1; e += 256) {
        const int2 ev = edges_in[e];
        const int rl = ((unsigned)ev.x) >> 18;
        const int pos = s0 + atomicAdd(&cur[rl], 1);
        edges_out[pos] = make_int2(ev.x & 0x3FFFF, ev.y);
    }
    if (b == NB - 1 && t == 0) offsets[ROW_PAD] = N_EDGES;
}

// ---------------- row-sum: one 16-lane sub owns the row ----------------
// Masked 8-edge batches: 8 edge loads + 8 row-gathers issued back-to-back,
// uniform control flow (index clamped, val zeroed for e >= end).
__device__ __forceinline__ float4 row_sum16(const int2* __restrict__ edges,
                                            const u16* __restrict__ x,
                                            int start, int end, int d0) {
    float4 s = {0.f, 0.f, 0.f, 0.f};
    for (int e0 = start; e0 < end; e0 += 8) {
        int2 E[8];
#pragma unroll
        for (int j = 0; j < 8; ++j) {
            const int ee = e0 + j;
            E[j] = edges[ee < end ? ee : end - 1];
        }
        ushort4 X[8];
#pragma unroll
        for (int j = 0; j < 8; ++j) {
            X[j] = *reinterpret_cast<const ushort4*>(x + (size_t)E[j].x * EMB + d0);
        }
#pragma unroll
        for (int j = 0; j < 8; ++j) {
            const float v = (e0 + j < end) ? __int_as_float(E[j].y) : 0.f;
            s.x += v * bf2f(X[j].x);
            s.y += v * bf2f(X[j].y);
            s.z += v * bf2f(X[j].z);
            s.w += v * bf2f(X[j].w);
        }
    }
    return s;
}

// ---------------- SpMM (gather, CSR, bf16 in / bf16 out) ----------------
// 4 rows per wave (one per 16-lane sub); no cross-lane reduce; coalesced store.
__global__ __launch_bounds__(256) void spmm_gather_bf16(
        const int* __restrict__ offsets, const int2* __restrict__ edges,
        const u16* __restrict__ x, u16* __restrict__ y) {
    const int wid = threadIdx.x >> 6;
    const int lane = threadIdx.x & 63;
    const int sub = lane >> 4;
    const int l16 = lane & 15;
    const int r = blockIdx.x * 16 + wid * 4 + sub;
    if (r >= N_NODES) return;

    const int start = offsets[r];
    const int end = offsets[r + 1];
    const int d0 = 4 * l16;
    const float4 s = row_sum16(edges, x, start, end, d0);

    ushort4 o;
    o.x = f2bf(s.x); o.y = f2bf(s.y); o.z = f2bf(s.z); o.w = f2bf(s.w);
    *reinterpret_cast<ushort4*>(y + (size_t)r * EMB + d0) = o;
}

// ---------------- final SpMM with fused combine ----------------
__global__ __launch_bounds__(256) void spmm_final(
        const int* __restrict__ offsets, const int2* __restrict__ edges,
        const u16* __restrict__ x, const u16* __restrict__ y1,
        const u16* __restrict__ y2, float* __restrict__ out) {
    const int wid = threadIdx.x >> 6;
    const int lane = threadIdx.x & 63;
    const int sub = lane >> 4;
    const int l16 = lane & 15;
    const int r = blockIdx.x * 16 + wid * 4 + sub;
    if (r >= N_NODES) return;

    const int start = offsets[r];
    const int end = offsets[r + 1];
    const int d0 = 4 * l16;
    const float4 s = row_sum16(edges, x, start, end, d0);

    const size_t o = (size_t)r * EMB + d0;
    const ushort4 a = *reinterpret_cast<const ushort4*>(y1 + o);
    const ushort4 b = *reinterpret_cast<const ushort4*>(y2 + o);
    const float sc = 1.0f / N_LAYERS;
    float4 ov;
    ov.x = (bf2f(a.x) + bf2f(b.x) + s.x) * sc;
    ov.y = (bf2f(a.y) + bf2f(b.y) + s.y) * sc;
    ov.z = (bf2f(a.z) + bf2f(b.z) + s.z) * sc;
    ov.w = (bf2f(a.w) + bf2f(b.w) + s.w) * sc;
    *reinterpret_cast<float4*>(out + o) = ov;
}

// ---------------- launch ----------------
extern "C" void kernel_launch(void* const* d_in, const int* in_sizes, int n_in,
                              void* d_out, int out_size, void* d_ws, size_t ws_size,
                              hipStream_t stream) {
    const float* user_emb = (const float*)d_in[0];
    const float* item_emb = (const float*)d_in[1];
    const int*   adj_rows = (const int*)d_in[2];
    const int*   adj_cols = (const int*)d_in[3];
    const float* adj_vals = (const float*)d_in[4];
    float* out = (float*)d_out;

    const size_t nodeElems = (size_t)N_NODES * EMB;  // 9.6M

    // workspace layout (~96.6 MB; cnt and offsets time-share one region)
    u16* b0 = (u16*)d_ws;                         // 19.2 MB
    u16* b1 = b0 + nodeElems;                     // 19.2 MB
    u16* b2 = b1 + nodeElems;                     // 19.2 MB
    int2* edges_tmp = (int2*)(b2 + nodeElems);    // 19.2 MB
    int2* edges_final = edges_tmp + N_EDGES;      // 19.2 MB
    int* unionReg = (int*)(edges_final + N_EDGES);
    int* cnt = unionReg;                          // NCHUNK_A*NB = 150016 ints
    int* offsets = unionReg;                      // ROW_PAD+1 = 150017 ints
    int* bstart = unionReg + 150024;              // NB+1
    int* gcursor = bstart + (NB + 1);             // NB

    concat_bf16_kernel<<<2048, 256, 0, stream>>>(user_emb, item_emb, b0);
    bucket_count<<<NCHUNK_A, 256, 0, stream>>>(adj_rows, cnt);
    bucket_scan<<<1, 256, 0, stream>>>(cnt, bstart, gcursor);
    bin_scatter<<<NCHUNK2, 256, 0, stream>>>(adj_rows, adj_cols, adj_vals,
                                             gcursor, edges_tmp);
    row_sort<<<NB, 256, 0, stream>>>(edges_tmp, bstart, offsets, edges_final);

    const int spmmGrid = (N_NODES + 15) / 16;  // 9375 blocks, 16 rows/block
    spmm_gather_bf16<<<spmmGrid, 256, 0, stream>>>(offsets, edges_final, b0, b1);
    spmm_gather_bf16<<<spmmGrid, 256, 0, stream>>>(offsets, edges_final, b1, b2);
    spmm_final<<<spmmGrid, 256, 0, stream>>>(offsets, edges_final, b2, b1, b2, out);
}